// Round 16
// baseline (162.519 us; speedup 1.0000x reference)
//
#include <hip/hip_runtime.h>
#include <hip/hip_bf16.h>

#define S_DIM 2048
#define D_DIM 512
#define B_DIM 8
#define SCALE 0.02209708691207961f  // 1/sqrt(2048)

typedef __hip_bfloat16 bf16;
typedef short bf16x8 __attribute__((ext_vector_type(8)));
typedef float f32x4 __attribute__((ext_vector_type(4)));

__device__ __forceinline__ unsigned short f2b(float f) {
  __hip_bfloat16 h = __float2bfloat16(f);
  return __builtin_bit_cast(unsigned short, h);
}
__device__ __forceinline__ float b2f(unsigned short s) {
  return __bfloat162float(__builtin_bit_cast(__hip_bfloat16, s));
}

__device__ __forceinline__ void load_lds16(const void* g, void* l) {
  __builtin_amdgcn_global_load_lds((const __attribute__((address_space(1))) void*)g,
                                   (__attribute__((address_space(3))) void*)l, 16, 0, 0);
}

// ---------------- fused prep: x1,x2 transpose+convert | K convert | rowsum zero --------
// z<16: 64x64 transpose via wide LDS ops (2x b128 write + 2x b128 read per thread):
//   phase A: thread owns one D-column, loads 16 f32 along S (coalesced 256B/instr),
//            converts, writes two 16B LDS rows-of-the-transposed-tile.
//   phase B: 8 threads per output row, b128 LDS read + 16B global store.
// z==16: K f32->bf16 + rowsum zero (unchanged).
__global__ void prep(const float* __restrict__ x1, const float* __restrict__ x2,
                     const float* __restrict__ km,
                     bf16* __restrict__ xt, bf16* __restrict__ Kbf,
                     float* __restrict__ rowsum) {
  const int z = blockIdx.z;
  const int tid = threadIdx.x;
  if (z == 16) {
    const int bid = blockIdx.y * 8 + blockIdx.x;   // 0..255
    const float4* p = (const float4*)km;
    bf16x8* o = (bf16x8*)Kbf;
#pragma unroll
    for (int it = 0; it < 8; it++) {
      int i = bid * 2048 + it * 256 + tid;
      float4 a = p[2 * i], b = p[2 * i + 1];
      bf16x8 r;
      r[0] = f2b(a.x); r[1] = f2b(a.y); r[2] = f2b(a.z); r[3] = f2b(a.w);
      r[4] = f2b(b.x); r[5] = f2b(b.y); r[6] = f2b(b.z); r[7] = f2b(b.w);
      o[i] = r;
    }
    if (bid < 8) {
      float4 zf = {0.0f, 0.0f, 0.0f, 0.0f};
      float4* rp = (float4*)(rowsum + bid * 2048);
      rp[tid * 2] = zf;
      rp[tid * 2 + 1] = zf;
    }
    return;
  }
  __shared__ unsigned short tt[64][72];   // [d][s]; 144B row stride (16B-aligned slots)
  const float* in = (z < 8 ? x1 : x2) + (size_t)(z & 7) * (S_DIM * D_DIM);
  bf16* ob = xt + (size_t)z * (size_t)(D_DIM * S_DIM);
  const int r0 = blockIdx.y * 64;   // S
  const int c0 = blockIdx.x * 64;   // D
  // phase A: c = column (output row), g = S-group
  const int c = tid & 63, g = tid >> 6;   // g 0..3
  {
    unsigned short u[16];
#pragma unroll
    for (int i = 0; i < 16; i++)
      u[i] = f2b(in[(size_t)(r0 + g * 16 + i) * D_DIM + c0 + c]);
    uint4 w0, w1;
    w0.x = (unsigned)u[0] | ((unsigned)u[1] << 16);
    w0.y = (unsigned)u[2] | ((unsigned)u[3] << 16);
    w0.z = (unsigned)u[4] | ((unsigned)u[5] << 16);
    w0.w = (unsigned)u[6] | ((unsigned)u[7] << 16);
    w1.x = (unsigned)u[8] | ((unsigned)u[9] << 16);
    w1.y = (unsigned)u[10] | ((unsigned)u[11] << 16);
    w1.z = (unsigned)u[12] | ((unsigned)u[13] << 16);
    w1.w = (unsigned)u[14] | ((unsigned)u[15] << 16);
    *(uint4*)&tt[c][g * 16] = w0;
    *(uint4*)&tt[c][g * 16 + 8] = w1;
  }
  __syncthreads();
  // phase B: 8 threads per output row
  const int dl = tid >> 3, tq = tid & 7;  // dl 0..31
#pragma unroll
  for (int p = 0; p < 2; p++) {
    int d = p * 32 + dl;
    uint4 u = *(const uint4*)&tt[d][tq * 8];
    *(uint4*)(ob + (size_t)(c0 + d) * S_DIM + r0 + tq * 8) = u;
  }
}

// ---------------- h-GEMM v5: R13 structure, setprio REMOVED (T5 null on lockstep) ------
__global__ __launch_bounds__(512, 1) void gemm_h(
    const bf16* __restrict__ A, const bf16* __restrict__ X, bf16* __restrict__ H) {
  extern __shared__ char smem[];
  const int pid = blockIdx.x;
  const int mt = pid & 7;              // XCD-pinned A panel
  const int r_ = pid >> 3;
  const int ntile = r_ & 1;
  const int item = r_ >> 1;            // 0..15
  const int m0 = mt * 256, n0 = ntile * 256;
  const bf16* Xi = X + (size_t)item * (D_DIM * S_DIM);
  bf16* Hi = H + (size_t)item * (S_DIM * D_DIM);

  const int tid = threadIdx.x;
  const int w = tid >> 6, L = tid & 63;
  const int l15 = L & 15, lhi = L >> 4;
  const int wr = w >> 2, wn = w & 3;

  const int srow = tid >> 3;                       // 0..63
  const int sslot = ((tid & 7) ^ (srow & 7)) * 8;  // elements
  const bf16* pA[4];
  const bf16* pB[4];
#pragma unroll
  for (int ld = 0; ld < 4; ld++) {
    pA[ld] = A + (size_t)(m0 + ld * 64 + srow) * 2048 + sslot;
    pB[ld] = Xi + (size_t)(n0 + ld * 64 + srow) * 2048 + sslot;
  }

  auto stage = [&](int t) {
    char* dA = smem + (t & 1) * 32768 + w * 1024;
    char* dB = smem + 65536 + (t & 1) * 32768 + w * 1024;
    const int ko = t * 64;
#pragma unroll
    for (int ld = 0; ld < 4; ld++) {
      load_lds16(pA[ld] + ko, dA + ld * 8192);
      load_lds16(pB[ld] + ko, dB + ld * 8192);
    }
  };

  const int xsw = l15 & 7;
  int offA0[8], offB0[4];
#pragma unroll
  for (int m = 0; m < 8; m++)
    offA0[m] = (wr * 128 + m * 16 + l15) * 128 + ((lhi ^ xsw) << 4);
#pragma unroll
  for (int n = 0; n < 4; n++)
    offB0[n] = (wn * 64 + n * 16 + l15) * 128 + ((lhi ^ xsw) << 4);

  f32x4 acc[8][4];
#pragma unroll
  for (int m = 0; m < 8; m++)
#pragma unroll
    for (int n = 0; n < 4; n++) acc[m][n] = (f32x4){0, 0, 0, 0};

  stage(0);
  asm volatile("s_waitcnt vmcnt(0)" ::: "memory");
  __builtin_amdgcn_s_barrier();
  asm volatile("" ::: "memory");

#pragma unroll 1
  for (int t = 0; t < 32; ++t) {
    if (t + 1 < 32) stage(t + 1);
    const char* bA = smem + (t & 1) * 32768;
    const char* bB = smem + 65536 + (t & 1) * 32768;
#pragma unroll
    for (int kk = 0; kk < 2; kk++) {
      bf16x8 af[8], bfv[4];
#pragma unroll
      for (int m = 0; m < 8; m++) af[m] = *(const bf16x8*)(bA + (offA0[m] ^ (kk << 6)));
#pragma unroll
      for (int n = 0; n < 4; n++) bfv[n] = *(const bf16x8*)(bB + (offB0[n] ^ (kk << 6)));
#pragma unroll
      for (int m = 0; m < 8; m++)
#pragma unroll
        for (int n = 0; n < 4; n++)
          acc[m][n] = __builtin_amdgcn_mfma_f32_16x16x32_bf16(bfv[n], af[m], acc[m][n], 0, 0, 0);
    }
    asm volatile("s_waitcnt vmcnt(0)" ::: "memory");
    __builtin_amdgcn_s_barrier();
    asm volatile("" ::: "memory");
  }

#pragma unroll
  for (int m = 0; m < 8; m++) {
    int grow = m0 + wr * 128 + m * 16 + l15;
#pragma unroll
    for (int n = 0; n < 4; n++) {
      int gcol = n0 + wn * 64 + n * 16 + lhi * 4;
      uint2 u;
      u.x = ((unsigned)f2b(acc[m][n][1]) << 16) | f2b(acc[m][n][0]);
      u.y = ((unsigned)f2b(acc[m][n][3]) << 16) | f2b(acc[m][n][2]);
      *(uint2*)(Hi + (size_t)grow * D_DIM + gcol) = u;
    }
  }
}

// ---------------- score GEMM + fused h1n->h1t transpose (R12-verbatim) ----------------
__global__ __launch_bounds__(512, 2) void gemm_score(
    const bf16* __restrict__ H1, const bf16* __restrict__ H2,
    bf16* __restrict__ E, float* __restrict__ rowsum, bf16* __restrict__ H1T) {
  extern __shared__ char smem[];
  const int pid = blockIdx.x;
  const int tid = threadIdx.x;

  if (pid >= 288) {
    const int tb = pid - 288;                 // 0..255
    const int half = tid >> 8;                // 0/1
    const int t5 = tid & 255;
    unsigned short (*tl)[66] = (unsigned short (*)[66])(smem + half * 8448);
    const int lr = t5 >> 4, lq = t5 & 15;
#pragma unroll 1
    for (int i = 0; i < 4; i++) {
      const int tile = tb * 8 + half * 4 + i;   // 0..2047
      const int z = tile >> 8;
      const int rem = tile & 255;
      const int r0 = (rem >> 3) * 64;           // S
      const int c0 = (rem & 7) * 64;            // D
      const bf16* ib = H1 + (size_t)z * (S_DIM * D_DIM);
      bf16* ob = H1T + (size_t)z * (S_DIM * D_DIM);
#pragma unroll
      for (int j = 0; j < 4; j++) {
        int r = j * 16 + lr;
        uint2 v = *(const uint2*)(ib + (size_t)(r0 + r) * D_DIM + c0 + lq * 4);
        tl[lq * 4 + 0][r] = (unsigned short)(v.x & 0xffff);
        tl[lq * 4 + 1][r] = (unsigned short)(v.x >> 16);
        tl[lq * 4 + 2][r] = (unsigned short)(v.y & 0xffff);
        tl[lq * 4 + 3][r] = (unsigned short)(v.y >> 16);
      }
      __syncthreads();
#pragma unroll
      for (int j = 0; j < 4; j++) {
        int d = j * 16 + lr;
        const unsigned short* p = &tl[d][lq * 4];
        uint2 u;
        u.x = (unsigned)p[0] | ((unsigned)p[1] << 16);
        u.y = (unsigned)p[2] | ((unsigned)p[3] << 16);
        *(uint2*)(ob + (size_t)(c0 + d) * S_DIM + r0 + lq * 4) = u;
      }
      __syncthreads();
    }
    return;
  }

  const int b = pid & 7;           // batch pinned to XCD
  const int tri = pid >> 3;        // 0..35
  int mt = (int)((sqrtf(8.0f * (float)tri + 1.0f) - 1.0f) * 0.5f);
  while ((mt + 1) * (mt + 2) / 2 <= tri) mt++;
  while (mt * (mt + 1) / 2 > tri) mt--;
  const int nt = tri - mt * (mt + 1) / 2;
  const int m0 = mt * 256, n0 = nt * 256;
  const bool diag = (mt == nt);
  const bf16* Ab = H1 + (size_t)b * S_DIM * D_DIM;
  const bf16* Bb = H2 + (size_t)b * S_DIM * D_DIM;
  bf16* Eb = E + (size_t)b * S_DIM * S_DIM;
  float* rs = rowsum + b * S_DIM;

  const int w = tid >> 6, L = tid & 63;
  const int l15 = L & 15, lhi = L >> 4;
  const int wr = w >> 2, wn = w & 3;

  const int srow = tid >> 2;
  const int sslot = ((tid & 3) ^ ((tid >> 3) & 3)) * 8;
  const bf16* pA[2];
  const bf16* pB[2];
#pragma unroll
  for (int ld = 0; ld < 2; ld++) {
    pA[ld] = Ab + (size_t)(m0 + ld * 128 + srow) * D_DIM + sslot;
    pB[ld] = Bb + (size_t)(n0 + ld * 128 + srow) * D_DIM + sslot;
  }

  auto stage = [&](int t) {
    char* dA = smem + (t & 1) * 16384;
    char* dB = smem + 32768 + (t & 1) * 16384;
#pragma unroll
    for (int ld = 0; ld < 2; ld++)
      load_lds16(pA[ld] + t * 32, dA + ld * 8192 + w * 1024);
#pragma unroll
    for (int ld = 0; ld < 2; ld++)
      load_lds16(pB[ld] + t * 32, dB + ld * 8192 + w * 1024);
  };

  const int xo = (lhi ^ ((l15 >> 1) & 3)) << 4;
  int offA[8], offB[4];
#pragma unroll
  for (int m = 0; m < 8; m++) offA[m] = (wr * 128 + m * 16 + l15) * 64 + xo;
#pragma unroll
  for (int n = 0; n < 4; n++) offB[n] = (wn * 64 + n * 16 + l15) * 64 + xo;

  f32x4 acc[8][4];
#pragma unroll
  for (int m = 0; m < 8; m++)
#pragma unroll
    for (int n = 0; n < 4; n++) acc[m][n] = (f32x4){0, 0, 0, 0};

  stage(0);
#pragma unroll 2
  for (int t = 0; t < 16; ++t) {
    __syncthreads();
    if (t + 1 < 16) stage(t + 1);
    const char* bA = smem + (t & 1) * 16384;
    const char* bB = smem + 32768 + (t & 1) * 16384;
    bf16x8 af[8], bfv[4];
#pragma unroll
    for (int m = 0; m < 8; m++) af[m] = *(const bf16x8*)(bA + offA[m]);
#pragma unroll
    for (int n = 0; n < 4; n++) bfv[n] = *(const bf16x8*)(bB + offB[n]);
    __builtin_amdgcn_s_setprio(1);
#pragma unroll
    for (int m = 0; m < 8; m++)
#pragma unroll
      for (int n = 0; n < 4; n++)
        acc[m][n] = __builtin_amdgcn_mfma_f32_16x16x32_bf16(bfv[n], af[m], acc[m][n], 0, 0, 0);
    __builtin_amdgcn_s_setprio(0);
  }

#pragma unroll
  for (int m = 0; m < 8; m++) {
    int sg = m0 + wr * 128 + m * 16 + l15;
    float rp = 0.0f;
#pragma unroll
    for (int n = 0; n < 4; n++) {
      int tg0 = n0 + wn * 64 + n * 16 + lhi * 4;
      unsigned short e[4];
#pragma unroll
      for (int r = 0; r < 4; r++) {
        float v = (!diag || (tg0 + r) <= sg) ? __expf(acc[m][n][r] * SCALE) : 0.0f;
        e[r] = f2b(v);
        rp += b2f(e[r]);
      }
      uint2 u;
      u.x = ((unsigned)e[1] << 16) | e[0];
      u.y = ((unsigned)e[3] << 16) | e[2];
      *(uint2*)(Eb + (size_t)sg * S_DIM + tg0) = u;
    }
    rp += __shfl_xor(rp, 16);
    rp += __shfl_xor(rp, 32);
    if (lhi == 0) atomicAdd(rs + sg, rp);
  }
}

// ---------------- PV GEMM v3 (R15-verbatim): 128x128xBK=128, dbuf, two m-tiles --------
__global__ __launch_bounds__(512, 1) void gemm_pv(
    const bf16* __restrict__ E, const bf16* __restrict__ H1T,
    const float* __restrict__ rowsum, float* __restrict__ out) {
  extern __shared__ char smem[];
  const int pid = blockIdx.x;
  const int b = pid & 7;           // XCD-pinned batch
  const int r_ = pid >> 3;         // 0..31
  const int nt = r_ & 3;
  const int mp = r_ >> 2;          // 0..7
  const int n0 = nt * 128;
  const bf16* Eb = E + (size_t)b * S_DIM * S_DIM;
  const bf16* Bb = H1T + (size_t)b * D_DIM * S_DIM + (size_t)n0 * S_DIM;
  const float* rs = rowsum + b * S_DIM;
  float* Cb = out + (size_t)b * S_DIM * D_DIM;

  const int tid = threadIdx.x;
  const int w = tid >> 6, L = tid & 63;
  const int l15 = L & 15, lhi = L >> 4;
  const int wr = w >> 2, wn = w & 3;

  const int srow = tid >> 4;                        // 0..31
  const int sslot = ((tid & 15) ^ (srow & 7)) * 8;  // elements (16 slots/row)
  const bf16* pB[4];
#pragma unroll
  for (int ld = 0; ld < 4; ld++)
    pB[ld] = Bb + (size_t)(ld * 32 + srow) * S_DIM + sslot;

  const int xsw = l15 & 7;
  int offA0[4], offB0[2];
#pragma unroll
  for (int m = 0; m < 4; m++)
    offA0[m] = (wr * 64 + m * 16 + l15) * 256 + ((lhi ^ xsw) << 4);
#pragma unroll
  for (int n = 0; n < 2; n++)
    offB0[n] = (wn * 32 + n * 16 + l15) * 256 + ((lhi ^ xsw) << 4);

#pragma unroll 1
  for (int ph = 0; ph < 2; ph++) {
    const int mt = ph ? (15 - mp) : mp;
    const int m0 = mt * 128;
    const int NT = mt + 1;                   // BK=128 steps
    const bf16* pA[4];
#pragma unroll
    for (int ld = 0; ld < 4; ld++)
      pA[ld] = Eb + (size_t)(m0 + ld * 32 + srow) * S_DIM + sslot;

    auto stage = [&](int t) {
      char* dA = smem + (t & 1) * 32768 + w * 1024;
      char* dB = smem + 65536 + (t & 1) * 32768 + w * 1024;
      const int ko = t * 128;
#pragma unroll
      for (int ld = 0; ld < 4; ld++) {
        load_lds16(pA[ld] + ko, dA + ld * 8192);
        load_lds16(pB[ld] + ko, dB + ld * 8192);
      }
    };

    f32x4 acc[4][2];
#pragma unroll
    for (int m = 0; m < 4; m++)
#pragma unroll
      for (int n = 0; n < 2; n++) acc[m][n] = (f32x4){0, 0, 0, 0};

    stage(0);
    asm volatile("s_waitcnt vmcnt(0)" ::: "memory");
    __builtin_amdgcn_s_barrier();
    asm volatile("" ::: "memory");

#pragma unroll 1
    for (int t = 0; t < NT; ++t) {
      if (t + 1 < NT) stage(t + 1);
      const char* bA = smem + (t & 1) * 32768;
      const char* bB = smem + 65536 + (t & 1) * 32768;
#pragma unroll
      for (int kk = 0; kk < 4; kk++) {
        bf16x8 af[4], bfv[2];
#pragma unroll
        for (int m = 0; m < 4; m++) af[m] = *(const bf16x8*)(bA + (offA0[m] ^ (kk << 6)));
#pragma unroll
        for (int n = 0; n < 2; n++) bfv[n] = *(const bf16x8*)(bB + (offB0[n] ^ (kk << 6)));
        __builtin_amdgcn_s_setprio(1);
#pragma unroll
        for (int m = 0; m < 4; m++)
#pragma unroll
          for (int n = 0; n < 2; n++)
            acc[m][n] = __builtin_amdgcn_mfma_f32_16x16x32_bf16(bfv[n], af[m], acc[m][n], 0, 0, 0);
        __builtin_amdgcn_s_setprio(0);
      }
      asm volatile("s_waitcnt vmcnt(0)" ::: "memory");
      __builtin_amdgcn_s_barrier();
      asm volatile("" ::: "memory");
    }

#pragma unroll
    for (int m = 0; m < 4; m++) {
      int sg = m0 + wr * 64 + m * 16 + l15;
      float inv = 1.0f / rs[sg];
#pragma unroll
      for (int n = 0; n < 2; n++) {
        int gcol = n0 + wn * 32 + n * 16 + lhi * 4;
        float4 o;
        o.x = acc[m][n][0] * inv;
        o.y = acc[m][n][1] * inv;
        o.z = acc[m][n][2] * inv;
        o.w = acc[m][n][3] * inv;
        *(float4*)(Cb + (size_t)sg * D_DIM + gcol) = o;
      }
    }
    __syncthreads();   // drain lgkm + barrier before phase-2 LDS reuse
  }
}

extern "C" void kernel_launch(void* const* d_in, const int* in_sizes, int n_in,
                              void* d_out, int out_size, void* d_ws, size_t ws_size,
                              hipStream_t stream) {
  const float* x1 = (const float*)d_in[0];
  const float* x2 = (const float*)d_in[1];
  const float* km = (const float*)d_in[2];
  float* out = (float*)d_out;
  char* ws = (char*)d_ws;
  // ws layout (bytes):
  //   [0,64M):   E (8 x 2048 x 2048 bf16) -- overlaps phase-1 temporaries below
  //   [0,8M):    Kbf | [8,24M): x1t | [24,40M): x2t   (dead before E is written)
  //   [64,80M):  h1n  [80,96M): h2n  [96,112M): h1t
  //   [112M,+64K): rowsum (8 x 2048 f32)
  bf16* E    = (bf16*)(ws);
  bf16* Kbf  = (bf16*)(ws);
  bf16* x1t  = (bf16*)(ws + (8ull << 20));
  bf16* h1n  = (bf16*)(ws + (64ull << 20));
  bf16* h2n  = (bf16*)(ws + (80ull << 20));
  bf16* h1t  = (bf16*)(ws + (96ull << 20));
  float* rowsum = (float*)(ws + (112ull << 20));

  prep<<<dim3(8, 32, 17), 256, 0, stream>>>(x1, x2, km, x1t, Kbf, rowsum);
  gemm_h<<<256, 512, 131072, stream>>>(Kbf, x1t, h1n);
  gemm_score<<<544, 512, 65536, stream>>>(h1n, h2n, E, rowsum, h1t);
  gemm_pv<<<256, 512, 131072, stream>>>(E, h1t, rowsum, out);
}

// Round 17
// 160.478 us; speedup vs baseline: 1.0127x; 1.0127x over previous
//
#include <hip/hip_runtime.h>
#include <hip/hip_bf16.h>

#define S_DIM 2048
#define D_DIM 512
#define B_DIM 8
#define SCALE 0.02209708691207961f  // 1/sqrt(2048)

typedef __hip_bfloat16 bf16;
typedef short bf16x8 __attribute__((ext_vector_type(8)));
typedef float f32x4 __attribute__((ext_vector_type(4)));

__device__ __forceinline__ unsigned short f2b(float f) {
  __hip_bfloat16 h = __float2bfloat16(f);
  return __builtin_bit_cast(unsigned short, h);
}
__device__ __forceinline__ float b2f(unsigned short s) {
  return __bfloat162float(__builtin_bit_cast(__hip_bfloat16, s));
}

__device__ __forceinline__ void load_lds16(const void* g, void* l) {
  __builtin_amdgcn_global_load_lds((const __attribute__((address_space(1))) void*)g,
                                   (__attribute__((address_space(3))) void*)l, 16, 0, 0);
}

// ---------------- fused prep (R16-verbatim): transpose+convert | K convert | rowsum ----
__global__ void prep(const float* __restrict__ x1, const float* __restrict__ x2,
                     const float* __restrict__ km,
                     bf16* __restrict__ xt, bf16* __restrict__ Kbf,
                     float* __restrict__ rowsum) {
  const int z = blockIdx.z;
  const int tid = threadIdx.x;
  if (z == 16) {
    const int bid = blockIdx.y * 8 + blockIdx.x;   // 0..255
    const float4* p = (const float4*)km;
    bf16x8* o = (bf16x8*)Kbf;
#pragma unroll
    for (int it = 0; it < 8; it++) {
      int i = bid * 2048 + it * 256 + tid;
      float4 a = p[2 * i], b = p[2 * i + 1];
      bf16x8 r;
      r[0] = f2b(a.x); r[1] = f2b(a.y); r[2] = f2b(a.z); r[3] = f2b(a.w);
      r[4] = f2b(b.x); r[5] = f2b(b.y); r[6] = f2b(b.z); r[7] = f2b(b.w);
      o[i] = r;
    }
    if (bid < 8) {
      float4 zf = {0.0f, 0.0f, 0.0f, 0.0f};
      float4* rp = (float4*)(rowsum + bid * 2048);
      rp[tid * 2] = zf;
      rp[tid * 2 + 1] = zf;
    }
    return;
  }
  __shared__ unsigned short tt[64][72];   // [d][s]; 144B row stride
  const float* in = (z < 8 ? x1 : x2) + (size_t)(z & 7) * (S_DIM * D_DIM);
  bf16* ob = xt + (size_t)z * (size_t)(D_DIM * S_DIM);
  const int r0 = blockIdx.y * 64;   // S
  const int c0 = blockIdx.x * 64;   // D
  const int c = tid & 63, g = tid >> 6;   // g 0..3
  {
    unsigned short u[16];
#pragma unroll
    for (int i = 0; i < 16; i++)
      u[i] = f2b(in[(size_t)(r0 + g * 16 + i) * D_DIM + c0 + c]);
    uint4 w0, w1;
    w0.x = (unsigned)u[0] | ((unsigned)u[1] << 16);
    w0.y = (unsigned)u[2] | ((unsigned)u[3] << 16);
    w0.z = (unsigned)u[4] | ((unsigned)u[5] << 16);
    w0.w = (unsigned)u[6] | ((unsigned)u[7] << 16);
    w1.x = (unsigned)u[8] | ((unsigned)u[9] << 16);
    w1.y = (unsigned)u[10] | ((unsigned)u[11] << 16);
    w1.z = (unsigned)u[12] | ((unsigned)u[13] << 16);
    w1.w = (unsigned)u[14] | ((unsigned)u[15] << 16);
    *(uint4*)&tt[c][g * 16] = w0;
    *(uint4*)&tt[c][g * 16 + 8] = w1;
  }
  __syncthreads();
  const int dl = tid >> 3, tq = tid & 7;  // dl 0..31
#pragma unroll
  for (int p = 0; p < 2; p++) {
    int d = p * 32 + dl;
    uint4 u = *(const uint4*)&tt[d][tq * 8];
    *(uint4*)(ob + (size_t)(c0 + d) * S_DIM + r0 + tq * 8) = u;
  }
}

// ---------------- h-GEMM v4 (R13-verbatim, 68.6us, setprio RESTORED) -------------------
__global__ __launch_bounds__(512, 1) void gemm_h(
    const bf16* __restrict__ A, const bf16* __restrict__ X, bf16* __restrict__ H) {
  extern __shared__ char smem[];
  const int pid = blockIdx.x;
  const int mt = pid & 7;              // XCD-pinned A panel
  const int r_ = pid >> 3;
  const int ntile = r_ & 1;
  const int item = r_ >> 1;            // 0..15
  const int m0 = mt * 256, n0 = ntile * 256;
  const bf16* Xi = X + (size_t)item * (D_DIM * S_DIM);
  bf16* Hi = H + (size_t)item * (S_DIM * D_DIM);

  const int tid = threadIdx.x;
  const int w = tid >> 6, L = tid & 63;
  const int l15 = L & 15, lhi = L >> 4;
  const int wr = w >> 2, wn = w & 3;

  const int srow = tid >> 3;                       // 0..63
  const int sslot = ((tid & 7) ^ (srow & 7)) * 8;  // elements
  const bf16* pA[4];
  const bf16* pB[4];
#pragma unroll
  for (int ld = 0; ld < 4; ld++) {
    pA[ld] = A + (size_t)(m0 + ld * 64 + srow) * 2048 + sslot;
    pB[ld] = Xi + (size_t)(n0 + ld * 64 + srow) * 2048 + sslot;
  }

  auto stage = [&](int t) {
    char* dA = smem + (t & 1) * 32768 + w * 1024;
    char* dB = smem + 65536 + (t & 1) * 32768 + w * 1024;
    const int ko = t * 64;
#pragma unroll
    for (int ld = 0; ld < 4; ld++) {
      load_lds16(pA[ld] + ko, dA + ld * 8192);
      load_lds16(pB[ld] + ko, dB + ld * 8192);
    }
  };

  const int xsw = l15 & 7;
  int offA0[8], offB0[4];
#pragma unroll
  for (int m = 0; m < 8; m++)
    offA0[m] = (wr * 128 + m * 16 + l15) * 128 + ((lhi ^ xsw) << 4);
#pragma unroll
  for (int n = 0; n < 4; n++)
    offB0[n] = (wn * 64 + n * 16 + l15) * 128 + ((lhi ^ xsw) << 4);

  f32x4 acc[8][4];
#pragma unroll
  for (int m = 0; m < 8; m++)
#pragma unroll
    for (int n = 0; n < 4; n++) acc[m][n] = (f32x4){0, 0, 0, 0};

  stage(0);
  asm volatile("s_waitcnt vmcnt(0)" ::: "memory");
  __builtin_amdgcn_s_barrier();
  asm volatile("" ::: "memory");

#pragma unroll 1
  for (int t = 0; t < 32; ++t) {
    if (t + 1 < 32) stage(t + 1);
    const char* bA = smem + (t & 1) * 32768;
    const char* bB = smem + 65536 + (t & 1) * 32768;
#pragma unroll
    for (int kk = 0; kk < 2; kk++) {
      bf16x8 af[8], bfv[4];
#pragma unroll
      for (int m = 0; m < 8; m++) af[m] = *(const bf16x8*)(bA + (offA0[m] ^ (kk << 6)));
#pragma unroll
      for (int n = 0; n < 4; n++) bfv[n] = *(const bf16x8*)(bB + (offB0[n] ^ (kk << 6)));
      __builtin_amdgcn_s_setprio(1);
#pragma unroll
      for (int m = 0; m < 8; m++)
#pragma unroll
        for (int n = 0; n < 4; n++)
          acc[m][n] = __builtin_amdgcn_mfma_f32_16x16x32_bf16(bfv[n], af[m], acc[m][n], 0, 0, 0);
      __builtin_amdgcn_s_setprio(0);
    }
    asm volatile("s_waitcnt vmcnt(0)" ::: "memory");
    __builtin_amdgcn_s_barrier();
    asm volatile("" ::: "memory");
  }

#pragma unroll
  for (int m = 0; m < 8; m++) {
    int grow = m0 + wr * 128 + m * 16 + l15;
#pragma unroll
    for (int n = 0; n < 4; n++) {
      int gcol = n0 + wn * 64 + n * 16 + lhi * 4;
      uint2 u;
      u.x = ((unsigned)f2b(acc[m][n][1]) << 16) | f2b(acc[m][n][0]);
      u.y = ((unsigned)f2b(acc[m][n][3]) << 16) | f2b(acc[m][n][2]);
      *(uint2*)(Hi + (size_t)grow * D_DIM + gcol) = u;
    }
  }
}

// ---------------- score GEMM + fused h1n->h1t transpose (R12-verbatim) ----------------
__global__ __launch_bounds__(512, 2) void gemm_score(
    const bf16* __restrict__ H1, const bf16* __restrict__ H2,
    bf16* __restrict__ E, float* __restrict__ rowsum, bf16* __restrict__ H1T) {
  extern __shared__ char smem[];
  const int pid = blockIdx.x;
  const int tid = threadIdx.x;

  if (pid >= 288) {
    const int tb = pid - 288;                 // 0..255
    const int half = tid >> 8;                // 0/1
    const int t5 = tid & 255;
    unsigned short (*tl)[66] = (unsigned short (*)[66])(smem + half * 8448);
    const int lr = t5 >> 4, lq = t5 & 15;
#pragma unroll 1
    for (int i = 0; i < 4; i++) {
      const int tile = tb * 8 + half * 4 + i;   // 0..2047
      const int z = tile >> 8;
      const int rem = tile & 255;
      const int r0 = (rem >> 3) * 64;           // S
      const int c0 = (rem & 7) * 64;            // D
      const bf16* ib = H1 + (size_t)z * (S_DIM * D_DIM);
      bf16* ob = H1T + (size_t)z * (S_DIM * D_DIM);
#pragma unroll
      for (int j = 0; j < 4; j++) {
        int r = j * 16 + lr;
        uint2 v = *(const uint2*)(ib + (size_t)(r0 + r) * D_DIM + c0 + lq * 4);
        tl[lq * 4 + 0][r] = (unsigned short)(v.x & 0xffff);
        tl[lq * 4 + 1][r] = (unsigned short)(v.x >> 16);
        tl[lq * 4 + 2][r] = (unsigned short)(v.y & 0xffff);
        tl[lq * 4 + 3][r] = (unsigned short)(v.y >> 16);
      }
      __syncthreads();
#pragma unroll
      for (int j = 0; j < 4; j++) {
        int d = j * 16 + lr;
        const unsigned short* p = &tl[d][lq * 4];
        uint2 u;
        u.x = (unsigned)p[0] | ((unsigned)p[1] << 16);
        u.y = (unsigned)p[2] | ((unsigned)p[3] << 16);
        *(uint2*)(ob + (size_t)(c0 + d) * S_DIM + r0 + lq * 4) = u;
      }
      __syncthreads();
    }
    return;
  }

  const int b = pid & 7;           // batch pinned to XCD
  const int tri = pid >> 3;        // 0..35
  int mt = (int)((sqrtf(8.0f * (float)tri + 1.0f) - 1.0f) * 0.5f);
  while ((mt + 1) * (mt + 2) / 2 <= tri) mt++;
  while (mt * (mt + 1) / 2 > tri) mt--;
  const int nt = tri - mt * (mt + 1) / 2;
  const int m0 = mt * 256, n0 = nt * 256;
  const bool diag = (mt == nt);
  const bf16* Ab = H1 + (size_t)b * S_DIM * D_DIM;
  const bf16* Bb = H2 + (size_t)b * S_DIM * D_DIM;
  bf16* Eb = E + (size_t)b * S_DIM * S_DIM;
  float* rs = rowsum + b * S_DIM;

  const int w = tid >> 6, L = tid & 63;
  const int l15 = L & 15, lhi = L >> 4;
  const int wr = w >> 2, wn = w & 3;

  const int srow = tid >> 2;
  const int sslot = ((tid & 3) ^ ((tid >> 3) & 3)) * 8;
  const bf16* pA[2];
  const bf16* pB[2];
#pragma unroll
  for (int ld = 0; ld < 2; ld++) {
    pA[ld] = Ab + (size_t)(m0 + ld * 128 + srow) * D_DIM + sslot;
    pB[ld] = Bb + (size_t)(n0 + ld * 128 + srow) * D_DIM + sslot;
  }

  auto stage = [&](int t) {
    char* dA = smem + (t & 1) * 16384;
    char* dB = smem + 32768 + (t & 1) * 16384;
#pragma unroll
    for (int ld = 0; ld < 2; ld++)
      load_lds16(pA[ld] + t * 32, dA + ld * 8192 + w * 1024);
#pragma unroll
    for (int ld = 0; ld < 2; ld++)
      load_lds16(pB[ld] + t * 32, dB + ld * 8192 + w * 1024);
  };

  const int xo = (lhi ^ ((l15 >> 1) & 3)) << 4;
  int offA[8], offB[4];
#pragma unroll
  for (int m = 0; m < 8; m++) offA[m] = (wr * 128 + m * 16 + l15) * 64 + xo;
#pragma unroll
  for (int n = 0; n < 4; n++) offB[n] = (wn * 64 + n * 16 + l15) * 64 + xo;

  f32x4 acc[8][4];
#pragma unroll
  for (int m = 0; m < 8; m++)
#pragma unroll
    for (int n = 0; n < 4; n++) acc[m][n] = (f32x4){0, 0, 0, 0};

  stage(0);
#pragma unroll 2
  for (int t = 0; t < 16; ++t) {
    __syncthreads();
    if (t + 1 < 16) stage(t + 1);
    const char* bA = smem + (t & 1) * 16384;
    const char* bB = smem + 32768 + (t & 1) * 16384;
    bf16x8 af[8], bfv[4];
#pragma unroll
    for (int m = 0; m < 8; m++) af[m] = *(const bf16x8*)(bA + offA[m]);
#pragma unroll
    for (int n = 0; n < 4; n++) bfv[n] = *(const bf16x8*)(bB + offB[n]);
    __builtin_amdgcn_s_setprio(1);
#pragma unroll
    for (int m = 0; m < 8; m++)
#pragma unroll
      for (int n = 0; n < 4; n++)
        acc[m][n] = __builtin_amdgcn_mfma_f32_16x16x32_bf16(bfv[n], af[m], acc[m][n], 0, 0, 0);
    __builtin_amdgcn_s_setprio(0);
  }

#pragma unroll
  for (int m = 0; m < 8; m++) {
    int sg = m0 + wr * 128 + m * 16 + l15;
    float rp = 0.0f;
#pragma unroll
    for (int n = 0; n < 4; n++) {
      int tg0 = n0 + wn * 64 + n * 16 + lhi * 4;
      unsigned short e[4];
#pragma unroll
      for (int r = 0; r < 4; r++) {
        float v = (!diag || (tg0 + r) <= sg) ? __expf(acc[m][n][r] * SCALE) : 0.0f;
        e[r] = f2b(v);
        rp += b2f(e[r]);
      }
      uint2 u;
      u.x = ((unsigned)e[1] << 16) | e[0];
      u.y = ((unsigned)e[3] << 16) | e[2];
      *(uint2*)(Eb + (size_t)sg * S_DIM + tg0) = u;
    }
    rp += __shfl_xor(rp, 16);
    rp += __shfl_xor(rp, 32);
    if (lhi == 0) atomicAdd(rs + sg, rp);
  }
}

// ---------------- PV GEMM v2 (R14-verbatim): 128x128xBK=64 double-buffer ---------------
__global__ __launch_bounds__(256, 2) void gemm_pv(
    const bf16* __restrict__ E, const bf16* __restrict__ H1T,
    const float* __restrict__ rowsum, float* __restrict__ out) {
  extern __shared__ char smem[];
  const int pid = blockIdx.x;
  const int b = pid & 7;
  const int r_ = pid >> 3;
  const int nt = r_ & 3;
  const int mb = r_ >> 2;
  const int mt = (mb < 8) ? 2 * mb : 31 - 2 * mb;   // depth-pairing across co-resident blocks
  const int m0 = mt * 128, n0 = nt * 128;
  const int NT = (mt + 1) * 2;     // K-tiles of 64
  const bf16* Ab = E + (size_t)b * S_DIM * S_DIM + (size_t)m0 * S_DIM;
  const bf16* Bb = H1T + (size_t)b * D_DIM * S_DIM + (size_t)n0 * S_DIM;
  const float* rs = rowsum + b * S_DIM;
  float* Cb = out + (size_t)b * S_DIM * D_DIM;

  const int tid = threadIdx.x;
  const int w = tid >> 6, L = tid & 63;
  const int l15 = L & 15, lhi = L >> 4;
  const int wr = w >> 1, wc = w & 1;

  const int srow = tid >> 3;                       // 0..31
  const int sslot = ((tid & 7) ^ (srow & 7)) * 8;  // elements
  const bf16* pA[4];
  const bf16* pB[4];
#pragma unroll
  for (int ld = 0; ld < 4; ld++) {
    pA[ld] = Ab + (size_t)(ld * 32 + srow) * S_DIM + sslot;
    pB[ld] = Bb + (size_t)(ld * 32 + srow) * S_DIM + sslot;
  }

  auto stage = [&](int t) {
    char* dA = smem + (t & 1) * 16384 + w * 1024;
    char* dB = smem + 32768 + (t & 1) * 16384 + w * 1024;
    const int ko = t * 64;
#pragma unroll
    for (int ld = 0; ld < 4; ld++) {
      load_lds16(pA[ld] + ko, dA + ld * 4096);
      load_lds16(pB[ld] + ko, dB + ld * 4096);
    }
  };

  const int xsw = l15 & 7;
  int offA0[4], offB0[4];
#pragma unroll
  for (int m = 0; m < 4; m++)
    offA0[m] = (wr * 64 + m * 16 + l15) * 128 + ((lhi ^ xsw) << 4);
#pragma unroll
  for (int n = 0; n < 4; n++)
    offB0[n] = (wc * 64 + n * 16 + l15) * 128 + ((lhi ^ xsw) << 4);

  f32x4 acc[4][4];
#pragma unroll
  for (int m = 0; m < 4; m++)
#pragma unroll
    for (int n = 0; n < 4; n++) acc[m][n] = (f32x4){0, 0, 0, 0};

  stage(0);
  asm volatile("s_waitcnt vmcnt(0)" ::: "memory");
  __builtin_amdgcn_s_barrier();
  asm volatile("" ::: "memory");

#pragma unroll 1
  for (int t = 0; t < NT; ++t) {
    if (t + 1 < NT) stage(t + 1);
    const char* bA = smem + (t & 1) * 16384;
    const char* bB = smem + 32768 + (t & 1) * 16384;
#pragma unroll
    for (int kk = 0; kk < 2; kk++) {
      bf16x8 af[4], bfv[4];
#pragma unroll
      for (int m = 0; m < 4; m++) af[m] = *(const bf16x8*)(bA + (offA0[m] ^ (kk << 6)));
#pragma unroll
      for (int n = 0; n < 4; n++) bfv[n] = *(const bf16x8*)(bB + (offB0[n] ^ (kk << 6)));
      __builtin_amdgcn_s_setprio(1);
#pragma unroll
      for (int m = 0; m < 4; m++)
#pragma unroll
        for (int n = 0; n < 4; n++)
          acc[m][n] = __builtin_amdgcn_mfma_f32_16x16x32_bf16(bfv[n], af[m], acc[m][n], 0, 0, 0);
      __builtin_amdgcn_s_setprio(0);
    }
    asm volatile("s_waitcnt vmcnt(0)" ::: "memory");
    __builtin_amdgcn_s_barrier();
    asm volatile("" ::: "memory");
  }

  // swapped layout: lane -> row m*16+l15, cols n*16+lhi*4+{0..3} -> float4 stores
#pragma unroll
  for (int m = 0; m < 4; m++) {
    int sg = m0 + wr * 64 + m * 16 + l15;
    float inv = 1.0f / rs[sg];
#pragma unroll
    for (int n = 0; n < 4; n++) {
      int gcol = n0 + wc * 64 + n * 16 + lhi * 4;
      float4 o;
      o.x = acc[m][n][0] * inv;
      o.y = acc[m][n][1] * inv;
      o.z = acc[m][n][2] * inv;
      o.w = acc[m][n][3] * inv;
      *(float4*)(Cb + (size_t)sg * D_DIM + gcol) = o;
    }
  }
}

extern "C" void kernel_launch(void* const* d_in, const int* in_sizes, int n_in,
                              void* d_out, int out_size, void* d_ws, size_t ws_size,
                              hipStream_t stream) {
  const float* x1 = (const float*)d_in[0];
  const float* x2 = (const float*)d_in[1];
  const float* km = (const float*)d_in[2];
  float* out = (float*)d_out;
  char* ws = (char*)d_ws;
  // ws layout (bytes):
  //   [0,64M):   E (8 x 2048 x 2048 bf16) -- overlaps phase-1 temporaries below
  //   [0,8M):    Kbf | [8,24M): x1t | [24,40M): x2t   (dead before E is written)
  //   [64,80M):  h1n  [80,96M): h2n  [96,112M): h1t
  //   [112M,+64K): rowsum (8 x 2048 f32)
  bf16* E    = (bf16*)(ws);
  bf16* Kbf  = (bf16*)(ws);
  bf16* x1t  = (bf16*)(ws + (8ull << 20));
  bf16* h1n  = (bf16*)(ws + (64ull << 20));
  bf16* h2n  = (bf16*)(ws + (80ull << 20));
  bf16* h1t  = (bf16*)(ws + (96ull << 20));
  float* rowsum = (float*)(ws + (112ull << 20));

  prep<<<dim3(8, 32, 17), 256, 0, stream>>>(x1, x2, km, x1t, Kbf, rowsum);
  gemm_h<<<256, 512, 131072, stream>>>(Kbf, x1t, h1n);
  gemm_score<<<544, 512, 65536, stream>>>(h1n, h2n, E, rowsum, h1t);
  gemm_pv<<<512, 256, 65536, stream>>>(E, h1t, rowsum, out);
}